// Round 4
// baseline (1879.338 us; speedup 1.0000x reference)
//
#include <hip/hip_runtime.h>
#include <stdint.h>

// Depthwise causal conv: y[b,c,p,q] = sum_{r<6,s<11} w[c,r,s]*xm[b,c,p+r-5,q+s-5]
// xm = x masked to lower triangle (h>=w); output masked to p>=q.
// N=2, C=16, H=W=2048.

#define HDIM 2048
#define WDIM 2048
#define CH   16
#define RTAP 6
#define STAP 11

#define TH 32            // output tile rows per block
#define TW 128           // output tile cols per block
#define LDSR 37          // TH + 5 top halo rows
#define GR   37          // 16B groups per LDS row: cols [q0-8, q0+140)
#define NSLOT (LDSR*GR)  // 1369
#define NJ 6             // ceil(NSLOT/256)

typedef const __attribute__((address_space(1))) uint32_t* gptr_t;
typedef __attribute__((address_space(3))) uint32_t* lptr_t;

__global__ __launch_bounds__(256, 3)
void dwconv_causal(const float* __restrict__ x, const float* __restrict__ wgt,
                   float* __restrict__ out) {
  const int bx = blockIdx.x, by = blockIdx.y, zp = blockIdx.z;
  const int q0 = bx * TW, p0 = by * TH;
  const int tid = threadIdx.x;
  const int tx = tid & 15, ty = tid >> 4;
  // Planes zp and zp+16: n=0/1, SAME channel zp -> same weights, same masks.
  const size_t pbase0 = (size_t)zp * HDIM * WDIM;
  const size_t pbase1 = (size_t)(zp + CH) * HDIM * WDIM;

  // Strictly-upper tile: zeros for both planes, no reads.
  if (p0 + TH - 1 < q0) {
    const float4 z = make_float4(0.f, 0.f, 0.f, 0.f);
    float* o0 = out + pbase0 + (size_t)p0 * WDIM + q0;
    float* o1 = out + pbase1 + (size_t)p0 * WDIM + q0;
#pragma unroll
    for (int i = 0; i < 4; ++i) {
      int idx = i * 256 + tid;
      int row = idx >> 5, c4 = idx & 31;  // 32 float4 per 128-col row
      *(float4*)(o0 + (size_t)row * WDIM + 4 * c4) = z;
      *(float4*)(o1 + (size_t)row * WDIM + 4 * c4) = z;
    }
    return;
  }

  __shared__ __attribute__((aligned(16))) float lds[2][NSLOT * 4];  // 42.7 KB

  // Weights: block-uniform -> scalar loads.
  const float* __restrict__ wc = wgt + zp * (RTAP * STAP);
  float wr[RTAP * STAP];
#pragma unroll
  for (int i = 0; i < RTAP * STAP; ++i) wr[i] = wc[i];

  // Per-thread staging slots (computed once; /37 magic-mul happens here only).
  int srow[NJ], scol[NJ];
#pragma unroll
  for (int j = 0; j < NJ; ++j) {
    int slot = j * 256 + tid;
    int row = slot / GR;
    int g = slot - row * GR;
    srow[j] = row;           // 0..36 -> input row p0-5+row
    scol[j] = 4 * g - 8;     // relative col of 16B group: q0-8 .. q0+136
  }

  const float* __restrict__ xp0 = x + pbase0;
  const float* __restrict__ xp1 = x + pbase1;

  // Pure: every staged element in-bounds AND causal (max col q0+139 <= min
  // row p0-5). bx>=1 keeps left halo >=0; bx<=14 keeps right halo <2048.
  const bool pure = (bx >= 1) && (bx <= 14) && (q0 + 144 <= p0);

  if (pure) {
    // Async global->LDS, linear dest (wave-uniform base + lane*16).
#pragma unroll
    for (int j = 0; j < NJ; ++j) {
      int slot = j * 256 + tid;
      if (slot < NSLOT) {  // prefix-contiguous lanes -> base rule OK
        size_t go = (size_t)(p0 - 5 + srow[j]) * WDIM + (q0 + scol[j]);
        __builtin_amdgcn_global_load_lds((gptr_t)(xp0 + go),
                                         (lptr_t)&lds[0][slot * 4], 16, 0, 0);
        __builtin_amdgcn_global_load_lds((gptr_t)(xp1 + go),
                                         (lptr_t)&lds[1][slot * 4], 16, 0, 0);
      }
    }
  } else {
    // Edge/diagonal: reg roundtrip with causal + bounds predication.
#pragma unroll
    for (int j = 0; j < NJ; ++j) {
      int slot = j * 256 + tid;
      if (slot < NSLOT) {
        int ih = p0 - 5 + srow[j];
        int cb = q0 + scol[j];
        float4 v0 = make_float4(0.f, 0.f, 0.f, 0.f);
        float4 v1 = make_float4(0.f, 0.f, 0.f, 0.f);
        if (ih >= 0) {
          bool fullv = (cb >= 0) && (cb + 3 <= ih) && (cb + 3 < WDIM);
          if (fullv) {
            v0 = *(const float4*)(xp0 + (size_t)ih * WDIM + cb);
            v1 = *(const float4*)(xp1 + (size_t)ih * WDIM + cb);
          } else {
#pragma unroll
            for (int e = 0; e < 4; ++e) {
              int iw = cb + e;
              if (iw >= 0 && iw < WDIM && iw <= ih) {
                (&v0.x)[e] = xp0[(size_t)ih * WDIM + iw];
                (&v1.x)[e] = xp1[(size_t)ih * WDIM + iw];
              }
            }
          }
        }
        *(float4*)&lds[0][slot * 4] = v0;
        *(float4*)&lds[1][slot * 4] = v1;
      }
    }
  }

  __syncthreads();  // drains vmcnt+lgkmcnt then barrier

  const bool fullcausal = (q0 + TW - 1 <= p0);

#pragma unroll 1
  for (int pl = 0; pl < 2; ++pl) {
    const float* __restrict__ lb = &lds[pl][0];
    float* __restrict__ op = out + (pl ? pbase1 : pbase0);

    float acc[2][8];
#pragma unroll
    for (int a = 0; a < 2; ++a)
#pragma unroll
      for (int b = 0; b < 8; ++b) acc[a][b] = 0.f;

#pragma unroll
    for (int ihl = 0; ihl < 7; ++ihl) {  // 7 LDS rows feed 2 output rows
      const int l = ty * 2 + ihl;
      // Window A: LDS float cols [4tx, 4tx+20)   (outputs q0+4tx..+3)
      // Window B: LDS float cols [64+4tx, ...)   (outputs q0+64+4tx..+3)
      float wa[20], wb[20];
#pragma unroll
      for (int k = 0; k < 5; ++k) {
        float4 ta = *(const float4*)&lb[(l * GR + tx + k) * 4];
        float4 tb = *(const float4*)&lb[(l * GR + 16 + tx + k) * 4];
        wa[4 * k + 0] = ta.x; wa[4 * k + 1] = ta.y;
        wa[4 * k + 2] = ta.z; wa[4 * k + 3] = ta.w;
        wb[4 * k + 0] = tb.x; wb[4 * k + 1] = tb.y;
        wb[4 * k + 2] = tb.z; wb[4 * k + 3] = tb.w;
      }
#pragma unroll
      for (int ro = 0; ro < 2; ++ro) {
        if (ro < ihl - 5 || ro > ihl) continue;  // const after unroll
        const int rr = ihl - ro;                 // tap row 0..5
#pragma unroll
        for (int s = 0; s < STAP; ++s) {
          const float wv = wr[rr * STAP + s];
#pragma unroll
          for (int cc = 0; cc < 4; ++cc) {
            acc[ro][cc]     += wv * wa[cc + s + 3];  // idx in [3,16]
            acc[ro][4 + cc] += wv * wb[cc + s + 3];
          }
        }
      }
    }

    // Stores: 16 lanes x float4 contiguous = 256B segments, fully coalesced.
#pragma unroll
    for (int ro = 0; ro < 2; ++ro) {
      const int p = p0 + ty * 2 + ro;
      if (!fullcausal) {
#pragma unroll
        for (int cc = 0; cc < 4; ++cc) {
          if (q0 + 4 * tx + cc > p) acc[ro][cc] = 0.f;
          if (q0 + 64 + 4 * tx + cc > p) acc[ro][4 + cc] = 0.f;
        }
      }
      *(float4*)(op + (size_t)p * WDIM + q0 + 4 * tx) =
          make_float4(acc[ro][0], acc[ro][1], acc[ro][2], acc[ro][3]);
      *(float4*)(op + (size_t)p * WDIM + q0 + 64 + 4 * tx) =
          make_float4(acc[ro][4], acc[ro][5], acc[ro][6], acc[ro][7]);
    }
  }
}

extern "C" void kernel_launch(void* const* d_in, const int* in_sizes, int n_in,
                              void* d_out, int out_size, void* d_ws, size_t ws_size,
                              hipStream_t stream) {
  const float* x   = (const float*)d_in[0];
  const float* wgt = (const float*)d_in[1];
  float* out       = (float*)d_out;
  dim3 grid(WDIM / TW, HDIM / TH, CH);  // (16, 64, 16); z = plane pair
  dwconv_causal<<<grid, dim3(256), 0, stream>>>(x, wgt, out);
}

// Round 5
// 542.207 us; speedup vs baseline: 3.4661x; 3.4661x over previous
//
#include <hip/hip_runtime.h>
#include <stdint.h>

// Depthwise causal conv: y[b,c,p,q] = sum_{r<6,s<11} w[c,r,s]*xm[b,c,p+r-5,q+s-5]
// xm = x masked to lower triangle (h>=w); output masked to p>=q.
// N=2, C=16, H=W=2048.  Structure = round-2 kernel (proven 323us), one change:
// TH 32->16 so 8 blocks/CU (32 waves, HW cap) destagger stage/compute phases.

#define HDIM 2048
#define WDIM 2048
#define CH   16
#define RTAP 6
#define STAP 11

#define TH 16            // output tile rows per block
#define TW 128           // output tile cols per block
#define LDSR 21          // TH + 5 halo rows
#define GR   37          // 16B groups per LDS row: cols [q0-8, q0+140)
#define NSLOT (LDSR*GR)  // 777 float4 slots = 12432 B -> 8 blocks/CU

typedef const __attribute__((address_space(1))) uint32_t* gptr_t;
typedef __attribute__((address_space(3))) uint32_t* lptr_t;

__global__ __launch_bounds__(256, 6)
void dwconv_causal(const float* __restrict__ x, const float* __restrict__ wgt,
                   float* __restrict__ out) {
  const int bx = blockIdx.x, by = blockIdx.y, plane = blockIdx.z;
  const int q0 = bx * TW, p0 = by * TH;
  const int tid = threadIdx.x;
  const size_t pb = (size_t)plane * HDIM * WDIM;
  const float* __restrict__ xp = x + pb;
  float* __restrict__ op = out + pb;

  // Strictly-upper tile: zeros, no reads, no LDS.
  if (p0 + TH - 1 < q0) {
    const float4 z = make_float4(0.f, 0.f, 0.f, 0.f);
#pragma unroll
    for (int i = 0; i < 2; ++i) {  // 16 rows x 32 float4
      int idx = i * 256 + tid;
      int row = idx >> 5, c4 = idx & 31;
      *(float4*)(op + (size_t)(p0 + row) * WDIM + q0 + 4 * c4) = z;
    }
    return;
  }

  __shared__ __attribute__((aligned(16))) float lds[NSLOT * 4];

  // Weights: block-uniform address -> scalar loads into SGPRs (round-2 proven:
  // VGPR=36/SGPR=96, no scratch).
  const float* __restrict__ wc = wgt + (plane & (CH - 1)) * (RTAP * STAP);
  float wr[RTAP * STAP];
#pragma unroll
  for (int i = 0; i < RTAP * STAP; ++i) wr[i] = wc[i];

  // Pure: every staged element in-bounds AND causal.
  // Staged cols span [q0-8, q0+139]; rows [p0-5, p0+15].
  // left halo >=0 -> bx>=1; right col q0+139<2048 -> bx<=14;
  // causal: q0+139 <= p0-5 -> p0 >= q0+144.
  const bool pure = (bx >= 1) && (bx <= 14) && (p0 >= q0 + 144);

  if (pure) {
    // Async global->LDS: linear dest (wave-uniform base + lane*16), no VGPR
    // roundtrip. Guard is prefix-contiguous in tid -> base-lane rule holds.
#pragma unroll
    for (int j = 0; j < 4; ++j) {
      int slot = j * 256 + tid;
      if (slot < NSLOT) {
        int row = slot / GR;
        int g = slot - row * GR;
        const float* ga = xp + (size_t)(p0 - 5 + row) * WDIM + (q0 - 8 + 4 * g);
        __builtin_amdgcn_global_load_lds((gptr_t)ga, (lptr_t)&lds[slot * 4],
                                         16, 0, 0);
      }
    }
  } else {
    // Edge/diagonal tile: reg roundtrip with causal + bounds predication.
#pragma unroll
    for (int j = 0; j < 4; ++j) {
      int slot = j * 256 + tid;
      if (slot < NSLOT) {
        int row = slot / GR;
        int g = slot - row * GR;
        int ih = p0 - 5 + row;
        int cb = q0 - 8 + 4 * g;
        float4 v = make_float4(0.f, 0.f, 0.f, 0.f);
        if (ih >= 0) {  // ih <= p0+15 <= 2047 always
          bool fullv = (cb >= 0) && (cb + 3 <= ih) && (cb + 3 < WDIM);
          if (fullv) {
            v = *(const float4*)(xp + (size_t)ih * WDIM + cb);
          } else {
            float* vv = &v.x;
#pragma unroll
            for (int e = 0; e < 4; ++e) {
              int iw = cb + e;
              if (iw >= 0 && iw < WDIM && iw <= ih)
                vv[e] = xp[(size_t)ih * WDIM + iw];
            }
          }
        }
        *(float4*)&lds[slot * 4] = v;
      }
    }
  }

  __syncthreads();

  // ---- Compute: 1 row x 8 cols per thread (round-2 window pattern) ----
  const int tx = tid & 15;   // col octet: cols q0+8tx .. +7
  const int ty = tid >> 4;   // output row p0+ty

  float acc[8];
#pragma unroll
  for (int c = 0; c < 8; ++c) acc[c] = 0.f;

#pragma unroll
  for (int r = 0; r < RTAP; ++r) {
    const int l = ty + r;            // LDS row (input row p0+ty+r-5)
    float xrow[24];                  // logical cols [8tx, 8tx+24) rel q0-8
#pragma unroll
    for (int k = 0; k < 6; ++k)
      *(float4*)&xrow[4 * k] = *(const float4*)&lds[(l * GR + 2 * tx + k) * 4];
    // bank = (20*l + 8*tx + 4k) mod 32 over the wave: uniform 8/bank. ok.
#pragma unroll
    for (int s = 0; s < STAP; ++s) {
      const float wv = wr[r * STAP + s];
#pragma unroll
      for (int cc = 0; cc < 8; ++cc)
        acc[cc] += wv * xrow[cc + s + 3];  // idx in [3,20]
    }
  }

  // ---- Store (two consecutive float4: 16 lanes cover 512B contiguous) ----
  const int p = p0 + ty;
  const int qb = q0 + 8 * tx;
  if (q0 + TW - 1 > p0) {  // tile crosses diagonal: apply causal mask
#pragma unroll
    for (int cc = 0; cc < 8; ++cc)
      if (qb + cc > p) acc[cc] = 0.f;
  }
  *(float4*)(op + (size_t)p * WDIM + qb) =
      make_float4(acc[0], acc[1], acc[2], acc[3]);
  *(float4*)(op + (size_t)p * WDIM + qb + 4) =
      make_float4(acc[4], acc[5], acc[6], acc[7]);
}

extern "C" void kernel_launch(void* const* d_in, const int* in_sizes, int n_in,
                              void* d_out, int out_size, void* d_ws, size_t ws_size,
                              hipStream_t stream) {
  const float* x   = (const float*)d_in[0];
  const float* wgt = (const float*)d_in[1];
  float* out       = (float*)d_out;
  dim3 grid(WDIM / TW, HDIM / TH, 2 * CH);  // (16, 128, 32)
  dwconv_causal<<<grid, dim3(256), 0, stream>>>(x, wgt, out);
}